// Round 10
// baseline (14391.385 us; speedup 1.0000x reference)
//
#include <hip/hip_runtime.h>
#include <hip/hip_bf16.h>
#include <cstdint>
#include <cstddef>

typedef float f32x4 __attribute__((ext_vector_type(4)));
typedef short s16x8 __attribute__((ext_vector_type(8)));

#define B_  256
#define T_  1024
#define D_  64
#define H_  512
#define O_  128
#define JW  16
#define NG  48

#define ROWW  192                   // u64 words per row (64 frags * 3)
#define SLABW 49152                 // u64 words per slab (256 rows * 192)

// ---- LDS layout (bytes) ----
#define OFF_WGH   0                 // [48][512] bf16 W_hh rows (swizzled)
#define OFF_WGI2  49152             // [48][512] bf16 W_comb rows
#define OFF_WGIX  98304             // [48][64]  bf16 W_ih x-part
#define OFF_WDEC  104448            // [16][512] bf16 W_dec slice (cg<8)
#define OFF_W0S   120832
#define OFF_C0S   121024
#define OFF_BIHS  121216
#define OFF_BHHS  121408
#define OFF_BDECS 121600
#define OFF_SCR   121728            // 2 waves * 16x16 u16 scratch (1024B)
#define SMEM_BYTES 122752           // >80KB -> 1 WG/CU

// ---- workspace layout (bytes) ----
#define WS_WCOMB 0                  // [1536][512] bf16
#define WS_C0    1572864            // [1536] f32
#define WS_HSLAB 1579008            // 2 slabs * 393216 B (epoch-tagged h words)
#define WS_HSZ   786432

__device__ inline f32x4 mfma16(s16x8 a, s16x8 b, f32x4 c) {
  return __builtin_amdgcn_mfma_f32_16x16x32_bf16(a, b, c, 0, 0, 0);
}

__device__ inline unsigned short f2bf(float f) {
  __hip_bfloat16 h = __float2bfloat16(f);
  unsigned short u;
  __builtin_memcpy(&u, &h, sizeof(u));
  return u;
}

__device__ inline s16x8 cvt8(const float* s) {
  union { unsigned short h[8]; s16x8 v; } p;
#pragma unroll
  for (int e = 0; e < 8; ++e) p.h[e] = f2bf(s[e]);
  return p.v;
}

// B-fragment readers (rows K-contiguous, 16B-block XOR swizzle by (row&7)<<4)
__device__ inline s16x8 fragK512(const char* base, int n, int kc, int kg) {
  int byteoff = n * 1024 + (((kc * 64) + (kg * 16)) ^ ((n & 7) << 4));
  return *(const s16x8*)(base + byteoff);
}
__device__ inline s16x8 fragK64(const char* base, int n, int kc, int kg) {
  int byteoff = n * 128 + (((kc * 64) + (kg * 16)) ^ ((n & 7) << 4));
  return *(const s16x8*)(base + byteoff);
}

__device__ inline unsigned long long ld64a(const unsigned long long* p) {
  return __hip_atomic_load(p, __ATOMIC_RELAXED, __HIP_MEMORY_SCOPE_AGENT);
}
__device__ inline void st64a(unsigned long long* p, unsigned long long v) {
  __hip_atomic_store(p, v, __ATOMIC_RELAXED, __HIP_MEMORY_SCOPE_AGENT);
}

// 3 epoch-tagged words -> one 8-bf16 MFMA A-fragment
__device__ inline s16x8 unpack3(unsigned long long w0, unsigned long long w1,
                                unsigned long long w2) {
  union { unsigned short u[8]; s16x8 v; } ua;
  ua.u[0] = (unsigned short)w0; ua.u[1] = (unsigned short)(w0 >> 16);
  ua.u[2] = (unsigned short)(w0 >> 32);
  ua.u[3] = (unsigned short)w1; ua.u[4] = (unsigned short)(w1 >> 16);
  ua.u[5] = (unsigned short)(w1 >> 32);
  ua.u[6] = (unsigned short)w2; ua.u[7] = (unsigned short)(w2 >> 16);
  return ua.v;
}

// batched epoch-verified fragment fetch: 48 words, 1 waitcnt, 1 check; retry whole batch
__device__ inline void fetch_frags(const unsigned long long* rq, int kg, unsigned tgt,
                                   s16x8* a, int& budget) {
  unsigned long long w[48];
#pragma unroll
  for (int f = 0; f < 16; ++f) {
    w[f * 3 + 0] = ld64a(rq + (size_t)(f * 4 + kg) * 3 + 0);
    w[f * 3 + 1] = ld64a(rq + (size_t)(f * 4 + kg) * 3 + 1);
    w[f * 3 + 2] = ld64a(rq + (size_t)(f * 4 + kg) * 3 + 2);
  }
  const unsigned long long tg = (unsigned long long)tgt;
  for (;;) {
    unsigned long long bad = 0;
#pragma unroll
    for (int i = 0; i < 48; ++i) bad |= (w[i] >> 48) ^ tg;
    if (!__any((int)(bad != 0))) break;
    if (--budget <= 0) break;
#pragma unroll
    for (int f = 0; f < 16; ++f) {
      w[f * 3 + 0] = ld64a(rq + (size_t)(f * 4 + kg) * 3 + 0);
      w[f * 3 + 1] = ld64a(rq + (size_t)(f * 4 + kg) * 3 + 1);
      w[f * 3 + 2] = ld64a(rq + (size_t)(f * 4 + kg) * 3 + 2);
    }
  }
#pragma unroll
  for (int kc = 0; kc < 16; ++kc)
    a[kc] = unpack3(w[kc * 3], w[kc * 3 + 1], w[kc * 3 + 2]);
}

// ---------------- W_comb = W_ih[:,1:65] @ W_dec[:64,:]  (+ c0) ----------------
__global__ void wcomb_kernel(const float* __restrict__ W_ih, const float* __restrict__ W_dec,
                             const float* __restrict__ b_ih, const float* __restrict__ b_dec,
                             unsigned short* __restrict__ Wcomb, float* __restrict__ c0) {
  __shared__ float arow[64];
  int i = blockIdx.x;
  int tid = threadIdx.x;
  if (tid < 64) arow[tid] = W_ih[(size_t)i * 65 + 1 + tid];
  __syncthreads();
  for (int j = tid; j < H_; j += 256) {
    float acc = 0.f;
#pragma unroll 8
    for (int d = 0; d < 64; ++d) acc += arow[d] * W_dec[(size_t)d * H_ + j];
    Wcomb[(size_t)i * H_ + j] = f2bf(acc);
  }
  if (tid == 0) {
    float acc = b_ih[i];
    for (int d = 0; d < 64; ++d) acc += arow[d] * b_dec[d];
    c0[i] = acc;
  }
}

// ---------------- persistent recurrence: batched epoch-in-data exchange ----------------
__global__ __launch_bounds__(128, 1) void rnn_persist(
    const float* __restrict__ xs, const float* __restrict__ ts,
    const float* __restrict__ W_ih, const float* __restrict__ W_hh,
    const float* __restrict__ b_ih, const float* __restrict__ b_hh,
    const float* __restrict__ W_dec, const float* __restrict__ b_dec,
    const int* __restrict__ cutoffp,
    const unsigned short* __restrict__ Wcomb, const float* __restrict__ c0,
    unsigned long long* __restrict__ hslabE, float* __restrict__ out) {
  extern __shared__ char sm[];
  const int tid = threadIdx.x;
  const int wave = tid >> 6, lane = tid & 63;
  const int jl = lane & 15, kg = lane >> 4;
  const int cutoff = *cutoffp;

  const int bg = blockIdx.x & 7;
  const int cg = blockIdx.x >> 3;
  const int b0 = bg * 32;
  const int j0 = cg * JW;

  // ---- one-time LDS fill (weights, swizzled; R2-proven layout) ----
  for (int u = tid; u < NG * 64; u += 128) {
    int r = u >> 6, blk = u & 63;
    int grow = (r >> 4) * H_ + j0 + (r & 15);
    s16x8 v = cvt8(W_hh + (size_t)grow * H_ + blk * 8);
    *(s16x8*)(sm + OFF_WGH + r * 1024 + ((blk * 16) ^ ((r & 7) << 4))) = v;
  }
  for (int u = tid; u < NG * 64; u += 128) {
    int r = u >> 6, blk = u & 63;
    int grow = (r >> 4) * H_ + j0 + (r & 15);
    s16x8 v = *(const s16x8*)(Wcomb + (size_t)grow * H_ + blk * 8);
    *(s16x8*)(sm + OFF_WGI2 + r * 1024 + ((blk * 16) ^ ((r & 7) << 4))) = v;
  }
  for (int u = tid; u < NG * 8; u += 128) {
    int r = u >> 3, blk = u & 7;
    int grow = (r >> 4) * H_ + j0 + (r & 15);
    s16x8 v = cvt8(W_ih + (size_t)grow * 65 + 1 + blk * 8);
    *(s16x8*)(sm + OFF_WGIX + r * 128 + ((blk * 16) ^ ((r & 7) << 4))) = v;
  }
  if (cg < 8) {
    for (int u = tid; u < 16 * 64; u += 128) {
      int r = u >> 6, blk = u & 63;
      s16x8 v = cvt8(W_dec + (size_t)(cg * 16 + r) * H_ + blk * 8);
      *(s16x8*)(sm + OFF_WDEC + r * 1024 + ((blk * 16) ^ ((r & 7) << 4))) = v;
    }
    if (tid < 16) ((float*)(sm + OFF_BDECS))[tid] = b_dec[cg * 16 + tid];
  }
  if (tid < NG) {
    int grow = (tid >> 4) * H_ + j0 + (tid & 15);
    ((float*)(sm + OFF_W0S))[tid]  = W_ih[(size_t)grow * 65];
    ((float*)(sm + OFF_C0S))[tid]  = c0[grow];
    ((float*)(sm + OFF_BIHS))[tid] = b_ih[grow];
    ((float*)(sm + OFF_BHHS))[tid] = b_hh[grow];
  }
  __syncthreads();

  const int mt = wave;                          // M-tile: 16 rows per wave
  const int rowg = b0 + mt * 16 + jl;           // A-frag row (per lane)
  const int hrow = b0 + mt * 16 + kg * 4;       // C-tile row base (per lane)
  unsigned short* scr = (unsigned short*)(sm + OFF_SCR) + mt * 256;
  int budget = 200000;

  const float* W0S  = (const float*)(sm + OFF_W0S);
  const float* C0S  = (const float*)(sm + OFF_C0S);
  const float* BIHS = (const float*)(sm + OFF_BIHS);
  const float* BHHS = (const float*)(sm + OFF_BHHS);
  const float w0r = W0S[jl],  w0z = W0S[16 + jl],  w0n = W0S[32 + jl];
  const float bir = BIHS[jl], biz = BIHS[16 + jl], bin_ = BIHS[32 + jl];
  const float c0r = C0S[jl],  c0z = C0S[16 + jl],  c0n = C0S[32 + jl];
  const float bhr = BHHS[jl], bhz = BHHS[16 + jl], bhn = BHHS[32 + jl];

  s16x8 whhf[3][16];
#pragma unroll
  for (int g = 0; g < 3; ++g)
#pragma unroll
    for (int kc = 0; kc < 16; ++kc)
      whhf[g][kc] = fragK512(sm + OFF_WGH, g * 16 + jl, kc, kg);

  const bool do_dec = (cg < 8);
  const float bd = do_dec ? ((const float*)(sm + OFF_BDECS))[jl] : 0.f;
  const int oc = cg * 16 + jl;                  // decode out-col

  float hp[4] = {0.f, 0.f, 0.f, 0.f};

  for (int t = 0; t < T_; ++t) {
    const bool use_x = (t < cutoff) || (t == 0);
    const unsigned tgt = (unsigned)t;           // epoch of h(t-1)
    const unsigned long long epw = (unsigned long long)(t + 1) << 48;
    const unsigned long long* rq =
        hslabE + (size_t)((t + 1) & 1) * SLABW + (size_t)rowg * ROWW;
    unsigned long long* wq = hslabE + (size_t)(t & 1) * SLABW;

    float tsv[4];
#pragma unroll
    for (int reg = 0; reg < 4; ++reg) tsv[reg] = ts[(size_t)(hrow + reg) * T_ + t];

    f32x4 g0{}, g1{}, g2{}, i0{}, i1{}, i2{};
    if (use_x) {                                 // xs-side gi: pre-exchange
      s16x8 ax0 = cvt8(xs + ((size_t)rowg * T_ + t) * D_ + kg * 8);
      s16x8 ax1 = cvt8(xs + ((size_t)rowg * T_ + t) * D_ + 32 + kg * 8);
      i0 = mfma16(ax0, fragK64(sm + OFF_WGIX, jl,      0, kg), i0);
      i1 = mfma16(ax0, fragK64(sm + OFF_WGIX, 16 + jl, 0, kg), i1);
      i2 = mfma16(ax0, fragK64(sm + OFF_WGIX, 32 + jl, 0, kg), i2);
      i0 = mfma16(ax1, fragK64(sm + OFF_WGIX, jl,      1, kg), i0);
      i1 = mfma16(ax1, fragK64(sm + OFF_WGIX, 16 + jl, 1, kg), i1);
      i2 = mfma16(ax1, fragK64(sm + OFF_WGIX, 32 + jl, 1, kg), i2);
    }

    s16x8 a[16];
    if (t > 0) {
      fetch_frags(rq, kg, tgt, a, budget);       // batched: ~1 RT common case
#pragma unroll
      for (int kc = 0; kc < 16; ++kc) {
        g0 = mfma16(a[kc], whhf[0][kc], g0);
        g1 = mfma16(a[kc], whhf[1][kc], g1);
        g2 = mfma16(a[kc], whhf[2][kc], g2);
      }
      if (!use_x) {
#pragma unroll
        for (int kc = 0; kc < 16; ++kc) {
          i0 = mfma16(a[kc], fragK512(sm + OFF_WGI2, jl,      kc, kg), i0);
          i1 = mfma16(a[kc], fragK512(sm + OFF_WGI2, 16 + jl, kc, kg), i1);
          i2 = mfma16(a[kc], fragK512(sm + OFF_WGI2, 32 + jl, kc, kg), i2);
        }
      }
    }

    // GRU in-register (all 6 gate tiles share (lane,reg) layout)
    unsigned short hb[4];
#pragma unroll
    for (int reg = 0; reg < 4; ++reg) {
      const float xr = i0[reg] + tsv[reg] * w0r + (use_x ? bir : c0r) + g0[reg] + bhr;
      const float xz = i1[reg] + tsv[reg] * w0z + (use_x ? biz : c0z) + g1[reg] + bhz;
      const float an = i2[reg] + tsv[reg] * w0n + (use_x ? bin_ : c0n);
      const float gn = g2[reg] + bhn;
      const float r = 1.f / (1.f + __expf(-xr));
      const float z = 1.f / (1.f + __expf(-xz));
      const float e2 = __expf(2.f * (an + r * gn));
      const float n = 1.f - 2.f / (e2 + 1.f);
      const float hn = (1.f - z) * n + z * hp[reg];
      hp[reg] = hn;
      hb[reg] = f2bf(hn);
    }

    // transpose via LDS scratch, pack 3 vals + epoch per word, store (NO drain, NO flag)
#pragma unroll
    for (int reg = 0; reg < 4; ++reg) scr[(kg * 4 + reg) * 16 + jl] = hb[reg];
    asm volatile("s_waitcnt lgkmcnt(0)" ::: "memory");
    __builtin_amdgcn_sched_barrier(0);
#pragma unroll
    for (int rep = 0; rep < 2; ++rep) {
      const int wi = lane + rep * 64;
      if (rep == 0 || lane < 32) {
        const int row = wi / 6, k = wi % 6;
        const int frag = k / 3, pos = k % 3;
        const int cb = frag * 8 + pos * 3;
        unsigned long long v =
            (unsigned long long)scr[row * 16 + cb] |
            ((unsigned long long)scr[row * 16 + cb + 1] << 16) |
            (pos < 2 ? ((unsigned long long)scr[row * 16 + cb + 2] << 32) : 0ull) |
            epw;
        st64a(wq + (size_t)(b0 + mt * 16 + row) * ROWW + (cg * 2 + frag) * 3 + pos, v);
      }
    }

    // off-chain: decode step t-1 from register fragments
    if (do_dec && t > 0) {
      f32x4 dacc{};
#pragma unroll
      for (int kc = 0; kc < 16; ++kc)
        dacc = mfma16(a[kc], fragK512(sm + OFF_WDEC, jl, kc, kg), dacc);
#pragma unroll
      for (int reg = 0; reg < 4; ++reg) {
        float vv = dacc[reg] + bd;
        if (oc >= D_) vv = fmaxf(vv, 0.001f);
        out[((size_t)(hrow + reg) * T_ + (t - 1)) * O_ + oc] = vv;
      }
    }
  }

  // epilogue: decode final step h(T-1)
  if (do_dec) {
    const unsigned long long* rq =
        hslabE + (size_t)((T_ - 1) & 1) * SLABW + (size_t)rowg * ROWW;
    s16x8 a[16];
    fetch_frags(rq, kg, (unsigned)T_, a, budget);
    f32x4 dacc{};
#pragma unroll
    for (int kc = 0; kc < 16; ++kc)
      dacc = mfma16(a[kc], fragK512(sm + OFF_WDEC, jl, kc, kg), dacc);
#pragma unroll
    for (int reg = 0; reg < 4; ++reg) {
      float vv = dacc[reg] + bd;
      if (oc >= D_) vv = fmaxf(vv, 0.001f);
      out[((size_t)(hrow + reg) * T_ + (T_ - 1)) * O_ + oc] = vv;
    }
  }
}

extern "C" void kernel_launch(void* const* d_in, const int* in_sizes, int n_in,
                              void* d_out, int out_size, void* d_ws, size_t ws_size,
                              hipStream_t stream) {
  const float* xs    = (const float*)d_in[0];
  const float* ts    = (const float*)d_in[1];
  const float* W_ih  = (const float*)d_in[2];
  const float* W_hh  = (const float*)d_in[3];
  const float* b_ih  = (const float*)d_in[4];
  const float* b_hh  = (const float*)d_in[5];
  const float* W_dec = (const float*)d_in[6];
  const float* b_dec = (const float*)d_in[7];
  const int* cutoff  = (const int*)d_in[8];
  float* out = (float*)d_out;

  char* ws = (char*)d_ws;
  unsigned short* Wcomb      = (unsigned short*)(ws + WS_WCOMB);
  float* c0                  = (float*)(ws + WS_C0);
  unsigned long long* hslabE = (unsigned long long*)(ws + WS_HSLAB);

  hipMemsetAsync(ws + WS_HSLAB, 0, WS_HSZ, stream);   // zero epochs (replay-safe)
  wcomb_kernel<<<1536, 256, 0, stream>>>(W_ih, W_dec, b_ih, b_dec, Wcomb, c0);
  hipFuncSetAttribute(reinterpret_cast<const void*>(rnn_persist),
                      hipFuncAttributeMaxDynamicSharedMemorySize, SMEM_BYTES);
  rnn_persist<<<256, 128, SMEM_BYTES, stream>>>(xs, ts, W_ih, W_hh, b_ih, b_hh,
                                                W_dec, b_dec, cutoff, Wcomb, c0,
                                                hslabE, out);
}

// Round 11
// 9188.130 us; speedup vs baseline: 1.5663x; 1.5663x over previous
//
#include <hip/hip_runtime.h>
#include <hip/hip_bf16.h>
#include <cstdint>
#include <cstddef>

typedef float f32x4 __attribute__((ext_vector_type(4)));
typedef short s16x8 __attribute__((ext_vector_type(8)));

#define B_  256
#define T_  1024
#define D_  64
#define H_  512
#define O_  128
#define JW  16
#define NG  48

#define ROWW  192                   // u64 words per row (64 frags * 3)
#define SLABW 49152                 // u64 words per slab (256 rows * 192)

// ---- LDS layout (bytes) ----
#define OFF_WGH   0                 // [48][512] bf16 W_hh rows (swizzled)
#define OFF_WGI2  49152             // [48][512] bf16 W_comb rows
#define OFF_WGIX  98304             // [48][64]  bf16 W_ih x-part
#define OFF_WDEC  104448            // [16][512] bf16 W_dec slice (cg<8)
#define OFF_W0S   120832
#define OFF_C0S   121024
#define OFF_BIHS  121216
#define OFF_BHHS  121408
#define OFF_BDECS 121600
#define OFF_SCR   121728            // 2 waves * 16x16 u16 scratch (1024B)
#define SMEM_BYTES 122752           // >80KB -> 1 WG/CU

// ---- workspace layout (bytes) ----
#define WS_WCOMB 0                  // [1536][512] bf16
#define WS_C0    1572864            // [1536] f32
#define WS_HSLAB 1579008            // 2 slabs * 393216 B (epoch-tagged h words)
#define WS_HSZ   786432

__device__ inline f32x4 mfma16(s16x8 a, s16x8 b, f32x4 c) {
  return __builtin_amdgcn_mfma_f32_16x16x32_bf16(a, b, c, 0, 0, 0);
}

__device__ inline unsigned short f2bf(float f) {
  __hip_bfloat16 h = __float2bfloat16(f);
  unsigned short u;
  __builtin_memcpy(&u, &h, sizeof(u));
  return u;
}

__device__ inline s16x8 cvt8(const float* s) {
  union { unsigned short h[8]; s16x8 v; } p;
#pragma unroll
  for (int e = 0; e < 8; ++e) p.h[e] = f2bf(s[e]);
  return p.v;
}

// B-fragment readers (rows K-contiguous, 16B-block XOR swizzle by (row&7)<<4)
__device__ inline s16x8 fragK512(const char* base, int n, int kc, int kg) {
  int byteoff = n * 1024 + (((kc * 64) + (kg * 16)) ^ ((n & 7) << 4));
  return *(const s16x8*)(base + byteoff);
}
__device__ inline s16x8 fragK64(const char* base, int n, int kc, int kg) {
  int byteoff = n * 128 + (((kc * 64) + (kg * 16)) ^ ((n & 7) << 4));
  return *(const s16x8*)(base + byteoff);
}

__device__ inline unsigned long long ld64a(const unsigned long long* p) {
  return __hip_atomic_load(p, __ATOMIC_RELAXED, __HIP_MEMORY_SCOPE_AGENT);
}
__device__ inline void st64a(unsigned long long* p, unsigned long long v) {
  __hip_atomic_store(p, v, __ATOMIC_RELAXED, __HIP_MEMORY_SCOPE_AGENT);
}

// 3 epoch-tagged words -> one 8-bf16 MFMA A-fragment
__device__ inline s16x8 unpack3(unsigned long long w0, unsigned long long w1,
                                unsigned long long w2) {
  union { unsigned short u[8]; s16x8 v; } ua;
  ua.u[0] = (unsigned short)w0; ua.u[1] = (unsigned short)(w0 >> 16);
  ua.u[2] = (unsigned short)(w0 >> 32);
  ua.u[3] = (unsigned short)w1; ua.u[4] = (unsigned short)(w1 >> 16);
  ua.u[5] = (unsigned short)(w1 >> 32);
  ua.u[6] = (unsigned short)w2; ua.u[7] = (unsigned short)(w2 >> 16);
  return ua.v;
}

// batched epoch-verified fragment fetch: 48 words, 1 waitcnt, 1 check; retry whole batch
__device__ inline void fetch_frags(const unsigned long long* rq, int kg, unsigned tgt,
                                   s16x8* a, int& budget) {
  unsigned long long w[48];
#pragma unroll
  for (int f = 0; f < 16; ++f) {
    w[f * 3 + 0] = ld64a(rq + (size_t)(f * 4 + kg) * 3 + 0);
    w[f * 3 + 1] = ld64a(rq + (size_t)(f * 4 + kg) * 3 + 1);
    w[f * 3 + 2] = ld64a(rq + (size_t)(f * 4 + kg) * 3 + 2);
  }
  const unsigned long long tg = (unsigned long long)tgt;
  for (;;) {
    unsigned long long bad = 0;
#pragma unroll
    for (int i = 0; i < 48; ++i) bad |= (w[i] >> 48) ^ tg;
    if (!__any((int)(bad != 0))) break;
    if (--budget <= 0) break;
#pragma unroll
    for (int f = 0; f < 16; ++f) {
      w[f * 3 + 0] = ld64a(rq + (size_t)(f * 4 + kg) * 3 + 0);
      w[f * 3 + 1] = ld64a(rq + (size_t)(f * 4 + kg) * 3 + 1);
      w[f * 3 + 2] = ld64a(rq + (size_t)(f * 4 + kg) * 3 + 2);
    }
  }
#pragma unroll
  for (int kc = 0; kc < 16; ++kc)
    a[kc] = unpack3(w[kc * 3], w[kc * 3 + 1], w[kc * 3 + 2]);
}

// ---------------- W_comb = W_ih[:,1:65] @ W_dec[:64,:]  (+ c0) ----------------
__global__ void wcomb_kernel(const float* __restrict__ W_ih, const float* __restrict__ W_dec,
                             const float* __restrict__ b_ih, const float* __restrict__ b_dec,
                             unsigned short* __restrict__ Wcomb, float* __restrict__ c0) {
  __shared__ float arow[64];
  int i = blockIdx.x;
  int tid = threadIdx.x;
  if (tid < 64) arow[tid] = W_ih[(size_t)i * 65 + 1 + tid];
  __syncthreads();
  for (int j = tid; j < H_; j += 256) {
    float acc = 0.f;
#pragma unroll 8
    for (int d = 0; d < 64; ++d) acc += arow[d] * W_dec[(size_t)d * H_ + j];
    Wcomb[(size_t)i * H_ + j] = f2bf(acc);
  }
  if (tid == 0) {
    float acc = b_ih[i];
    for (int d = 0; d < 64; ++d) acc += arow[d] * b_dec[d];
    c0[i] = acc;
  }
}

// ---------------- persistent recurrence: batched epoch-in-data, LDS weights ----------------
__global__ __launch_bounds__(128, 1) void rnn_persist(
    const float* __restrict__ xs, const float* __restrict__ ts,
    const float* __restrict__ W_ih, const float* __restrict__ W_hh,
    const float* __restrict__ b_ih, const float* __restrict__ b_hh,
    const float* __restrict__ W_dec, const float* __restrict__ b_dec,
    const int* __restrict__ cutoffp,
    const unsigned short* __restrict__ Wcomb, const float* __restrict__ c0,
    unsigned long long* __restrict__ hslabE, float* __restrict__ out) {
  extern __shared__ char sm[];
  const int tid = threadIdx.x;
  const int wave = tid >> 6, lane = tid & 63;
  const int jl = lane & 15, kg = lane >> 4;
  const int cutoff = *cutoffp;

  const int bg = blockIdx.x & 7;
  const int cg = blockIdx.x >> 3;
  const int b0 = bg * 32;
  const int j0 = cg * JW;

  // ---- one-time LDS fill (weights, swizzled; R2-proven layout) ----
  for (int u = tid; u < NG * 64; u += 128) {
    int r = u >> 6, blk = u & 63;
    int grow = (r >> 4) * H_ + j0 + (r & 15);
    s16x8 v = cvt8(W_hh + (size_t)grow * H_ + blk * 8);
    *(s16x8*)(sm + OFF_WGH + r * 1024 + ((blk * 16) ^ ((r & 7) << 4))) = v;
  }
  for (int u = tid; u < NG * 64; u += 128) {
    int r = u >> 6, blk = u & 63;
    int grow = (r >> 4) * H_ + j0 + (r & 15);
    s16x8 v = *(const s16x8*)(Wcomb + (size_t)grow * H_ + blk * 8);
    *(s16x8*)(sm + OFF_WGI2 + r * 1024 + ((blk * 16) ^ ((r & 7) << 4))) = v;
  }
  for (int u = tid; u < NG * 8; u += 128) {
    int r = u >> 3, blk = u & 7;
    int grow = (r >> 4) * H_ + j0 + (r & 15);
    s16x8 v = cvt8(W_ih + (size_t)grow * 65 + 1 + blk * 8);
    *(s16x8*)(sm + OFF_WGIX + r * 128 + ((blk * 16) ^ ((r & 7) << 4))) = v;
  }
  if (cg < 8) {
    for (int u = tid; u < 16 * 64; u += 128) {
      int r = u >> 6, blk = u & 63;
      s16x8 v = cvt8(W_dec + (size_t)(cg * 16 + r) * H_ + blk * 8);
      *(s16x8*)(sm + OFF_WDEC + r * 1024 + ((blk * 16) ^ ((r & 7) << 4))) = v;
    }
    if (tid < 16) ((float*)(sm + OFF_BDECS))[tid] = b_dec[cg * 16 + tid];
  }
  if (tid < NG) {
    int grow = (tid >> 4) * H_ + j0 + (tid & 15);
    ((float*)(sm + OFF_W0S))[tid]  = W_ih[(size_t)grow * 65];
    ((float*)(sm + OFF_C0S))[tid]  = c0[grow];
    ((float*)(sm + OFF_BIHS))[tid] = b_ih[grow];
    ((float*)(sm + OFF_BHHS))[tid] = b_hh[grow];
  }
  __syncthreads();

  const int mt = wave;                          // M-tile: 16 rows per wave
  const int rowg = b0 + mt * 16 + jl;           // A-frag row (per lane)
  const int hrow = b0 + mt * 16 + kg * 4;       // C-tile row base (per lane)
  unsigned short* scr = (unsigned short*)(sm + OFF_SCR) + mt * 256;
  int budget = 200000;

  const float* W0S  = (const float*)(sm + OFF_W0S);
  const float* C0S  = (const float*)(sm + OFF_C0S);
  const float* BIHS = (const float*)(sm + OFF_BIHS);
  const float* BHHS = (const float*)(sm + OFF_BHHS);
  const float w0r = W0S[jl],  w0z = W0S[16 + jl],  w0n = W0S[32 + jl];
  const float bir = BIHS[jl], biz = BIHS[16 + jl], bin_ = BIHS[32 + jl];
  const float c0r = C0S[jl],  c0z = C0S[16 + jl],  c0n = C0S[32 + jl];
  const float bhr = BHHS[jl], bhz = BHHS[16 + jl], bhn = BHHS[32 + jl];

  const bool do_dec = (cg < 8);
  const float bd = do_dec ? ((const float*)(sm + OFF_BDECS))[jl] : 0.f;
  const int oc = cg * 16 + jl;                  // decode out-col

  float hp[4] = {0.f, 0.f, 0.f, 0.f};

  for (int t = 0; t < T_; ++t) {
    const bool use_x = (t < cutoff) || (t == 0);
    const unsigned tgt = (unsigned)t;           // epoch of h(t-1)
    const unsigned long long epw = (unsigned long long)(t + 1) << 48;
    const unsigned long long* rq =
        hslabE + (size_t)((t + 1) & 1) * SLABW + (size_t)rowg * ROWW;
    unsigned long long* wq = hslabE + (size_t)(t & 1) * SLABW;

    float tsv[4];
#pragma unroll
    for (int reg = 0; reg < 4; ++reg) tsv[reg] = ts[(size_t)(hrow + reg) * T_ + t];

    f32x4 g0{}, g1{}, g2{}, i0{}, i1{}, i2{};
    if (use_x) {                                 // xs-side gi: pre-exchange
      s16x8 ax0 = cvt8(xs + ((size_t)rowg * T_ + t) * D_ + kg * 8);
      s16x8 ax1 = cvt8(xs + ((size_t)rowg * T_ + t) * D_ + 32 + kg * 8);
      i0 = mfma16(ax0, fragK64(sm + OFF_WGIX, jl,      0, kg), i0);
      i1 = mfma16(ax0, fragK64(sm + OFF_WGIX, 16 + jl, 0, kg), i1);
      i2 = mfma16(ax0, fragK64(sm + OFF_WGIX, 32 + jl, 0, kg), i2);
      i0 = mfma16(ax1, fragK64(sm + OFF_WGIX, jl,      1, kg), i0);
      i1 = mfma16(ax1, fragK64(sm + OFF_WGIX, 16 + jl, 1, kg), i1);
      i2 = mfma16(ax1, fragK64(sm + OFF_WGIX, 32 + jl, 1, kg), i2);
    }

    s16x8 a[16];
    if (t > 0) {
      fetch_frags(rq, kg, tgt, a, budget);       // batched: ~1 RT common case
      // all B-fragments from LDS (no register weight cache -> no spills)
#pragma unroll
      for (int kc = 0; kc < 16; ++kc) {
        g0 = mfma16(a[kc], fragK512(sm + OFF_WGH, jl,      kc, kg), g0);
        g1 = mfma16(a[kc], fragK512(sm + OFF_WGH, 16 + jl, kc, kg), g1);
        g2 = mfma16(a[kc], fragK512(sm + OFF_WGH, 32 + jl, kc, kg), g2);
      }
      if (!use_x) {
#pragma unroll
        for (int kc = 0; kc < 16; ++kc) {
          i0 = mfma16(a[kc], fragK512(sm + OFF_WGI2, jl,      kc, kg), i0);
          i1 = mfma16(a[kc], fragK512(sm + OFF_WGI2, 16 + jl, kc, kg), i1);
          i2 = mfma16(a[kc], fragK512(sm + OFF_WGI2, 32 + jl, kc, kg), i2);
        }
      }
    }

    // GRU in-register (all 6 gate tiles share (lane,reg) layout)
    unsigned short hb[4];
#pragma unroll
    for (int reg = 0; reg < 4; ++reg) {
      const float xr = i0[reg] + tsv[reg] * w0r + (use_x ? bir : c0r) + g0[reg] + bhr;
      const float xz = i1[reg] + tsv[reg] * w0z + (use_x ? biz : c0z) + g1[reg] + bhz;
      const float an = i2[reg] + tsv[reg] * w0n + (use_x ? bin_ : c0n);
      const float gn = g2[reg] + bhn;
      const float r = 1.f / (1.f + __expf(-xr));
      const float z = 1.f / (1.f + __expf(-xz));
      const float e2 = __expf(2.f * (an + r * gn));
      const float n = 1.f - 2.f / (e2 + 1.f);
      const float hn = (1.f - z) * n + z * hp[reg];
      hp[reg] = hn;
      hb[reg] = f2bf(hn);
    }

    // transpose via LDS scratch, pack 3 vals + epoch per word, store (NO drain, NO flag)
#pragma unroll
    for (int reg = 0; reg < 4; ++reg) scr[(kg * 4 + reg) * 16 + jl] = hb[reg];
    asm volatile("s_waitcnt lgkmcnt(0)" ::: "memory");
    __builtin_amdgcn_sched_barrier(0);
#pragma unroll
    for (int rep = 0; rep < 2; ++rep) {
      const int wi = lane + rep * 64;
      if (rep == 0 || lane < 32) {
        const int row = wi / 6, k = wi % 6;
        const int frag = k / 3, pos = k % 3;
        const int cb = frag * 8 + pos * 3;
        unsigned long long v =
            (unsigned long long)scr[row * 16 + cb] |
            ((unsigned long long)scr[row * 16 + cb + 1] << 16) |
            (pos < 2 ? ((unsigned long long)scr[row * 16 + cb + 2] << 32) : 0ull) |
            epw;
        st64a(wq + (size_t)(b0 + mt * 16 + row) * ROWW + (cg * 2 + frag) * 3 + pos, v);
      }
    }

    // off-chain: decode step t-1 from register fragments
    if (do_dec && t > 0) {
      f32x4 dacc{};
#pragma unroll
      for (int kc = 0; kc < 16; ++kc)
        dacc = mfma16(a[kc], fragK512(sm + OFF_WDEC, jl, kc, kg), dacc);
#pragma unroll
      for (int reg = 0; reg < 4; ++reg) {
        float vv = dacc[reg] + bd;
        if (oc >= D_) vv = fmaxf(vv, 0.001f);
        out[((size_t)(hrow + reg) * T_ + (t - 1)) * O_ + oc] = vv;
      }
    }
  }

  // epilogue: decode final step h(T-1)
  if (do_dec) {
    const unsigned long long* rq =
        hslabE + (size_t)((T_ - 1) & 1) * SLABW + (size_t)rowg * ROWW;
    s16x8 a[16];
    fetch_frags(rq, kg, (unsigned)T_, a, budget);
    f32x4 dacc{};
#pragma unroll
    for (int kc = 0; kc < 16; ++kc)
      dacc = mfma16(a[kc], fragK512(sm + OFF_WDEC, jl, kc, kg), dacc);
#pragma unroll
    for (int reg = 0; reg < 4; ++reg) {
      float vv = dacc[reg] + bd;
      if (oc >= D_) vv = fmaxf(vv, 0.001f);
      out[((size_t)(hrow + reg) * T_ + (T_ - 1)) * O_ + oc] = vv;
    }
  }
}

extern "C" void kernel_launch(void* const* d_in, const int* in_sizes, int n_in,
                              void* d_out, int out_size, void* d_ws, size_t ws_size,
                              hipStream_t stream) {
  const float* xs    = (const float*)d_in[0];
  const float* ts    = (const float*)d_in[1];
  const float* W_ih  = (const float*)d_in[2];
  const float* W_hh  = (const float*)d_in[3];
  const float* b_ih  = (const float*)d_in[4];
  const float* b_hh  = (const float*)d_in[5];
  const float* W_dec = (const float*)d_in[6];
  const float* b_dec = (const float*)d_in[7];
  const int* cutoff  = (const int*)d_in[8];
  float* out = (float*)d_out;

  char* ws = (char*)d_ws;
  unsigned short* Wcomb      = (unsigned short*)(ws + WS_WCOMB);
  float* c0                  = (float*)(ws + WS_C0);
  unsigned long long* hslabE = (unsigned long long*)(ws + WS_HSLAB);

  hipMemsetAsync(ws + WS_HSLAB, 0, WS_HSZ, stream);   // zero epochs (replay-safe)
  wcomb_kernel<<<1536, 256, 0, stream>>>(W_ih, W_dec, b_ih, b_dec, Wcomb, c0);
  hipFuncSetAttribute(reinterpret_cast<const void*>(rnn_persist),
                      hipFuncAttributeMaxDynamicSharedMemorySize, SMEM_BYTES);
  rnn_persist<<<256, 128, SMEM_BYTES, stream>>>(xs, ts, W_ih, W_hh, b_ih, b_hh,
                                                W_dec, b_dec, cutoff, Wcomb, c0,
                                                hslabE, out);
}

// Round 12
// 5108.559 us; speedup vs baseline: 2.8171x; 1.7986x over previous
//
#include <hip/hip_runtime.h>
#include <hip/hip_bf16.h>
#include <cstdint>
#include <cstddef>

typedef float f32x4 __attribute__((ext_vector_type(4)));
typedef short s16x8 __attribute__((ext_vector_type(8)));

#define B_  256
#define T_  1024
#define D_  64
#define H_  512
#define O_  128
#define JW  16
#define NG  48

#define SLABW64 32768               // u64 words per slab (256*512 bf16 / 4)

// ---- LDS layout (bytes) ----
#define OFF_WGH   0                 // [48][512] bf16 W_hh rows (swizzled)
#define OFF_WGI2  49152             // [48][512] bf16 W_comb rows
#define OFF_WGIX  98304             // [48][64]  bf16 W_ih x-part
#define OFF_WDEC  104448            // [16][512] bf16 W_dec slice (cg<8)
#define OFF_W0S   120832
#define OFF_C0S   121024
#define OFF_BIHS  121216
#define OFF_BHHS  121408
#define OFF_BDECS 121600
#define OFF_SCR   121728            // 2 waves * 16x16 u16 scratch (1024B)
#define SMEM_BYTES 122752           // >80KB -> 1 WG/CU

// ---- workspace layout (bytes) ----
#define WS_WCOMB 0                  // [1536][512] bf16
#define WS_C0    1572864            // [1536] f32
#define WS_HSLAB 1579008            // 2 slabs * 262144 B (fragment-layout h)
#define WS_CFLG  2103296            // 8 rings * 64 uint = 2048 B
#define WS_CTLSZ 2048

__device__ inline f32x4 mfma16(s16x8 a, s16x8 b, f32x4 c) {
  return __builtin_amdgcn_mfma_f32_16x16x32_bf16(a, b, c, 0, 0, 0);
}

__device__ inline unsigned short f2bf(float f) {
  __hip_bfloat16 h = __float2bfloat16(f);
  unsigned short u;
  __builtin_memcpy(&u, &h, sizeof(u));
  return u;
}

__device__ inline s16x8 cvt8(const float* s) {
  union { unsigned short h[8]; s16x8 v; } p;
#pragma unroll
  for (int e = 0; e < 8; ++e) p.h[e] = f2bf(s[e]);
  return p.v;
}

// B-fragment readers (rows K-contiguous, 16B-block XOR swizzle by (row&7)<<4)
__device__ inline s16x8 fragK512(const char* base, int n, int kc, int kg) {
  int byteoff = n * 1024 + (((kc * 64) + (kg * 16)) ^ ((n & 7) << 4));
  return *(const s16x8*)(base + byteoff);
}
__device__ inline s16x8 fragK64(const char* base, int n, int kc, int kg) {
  int byteoff = n * 128 + (((kc * 64) + (kg * 16)) ^ ((n & 7) << 4));
  return *(const s16x8*)(base + byteoff);
}

__device__ inline unsigned long long ld64a(const unsigned long long* p) {
  return __hip_atomic_load(p, __ATOMIC_RELAXED, __HIP_MEMORY_SCOPE_AGENT);
}
__device__ inline void st64a(unsigned long long* p, unsigned long long v) {
  __hip_atomic_store(p, v, __ATOMIC_RELAXED, __HIP_MEMORY_SCOPE_AGENT);
}

// fragment load: two consecutive u64 (coherent-point) -> 8 bf16
__device__ inline s16x8 ld_frag2(const unsigned long long* p) {
  union { unsigned long long q[2]; s16x8 v; } u;
  u.q[0] = ld64a(p);
  u.q[1] = ld64a(p + 1);
  return u.v;
}

// all 64 lanes poll one ring slot each (64 slots = 32 WGs x 2 waves) — R8-proven
__device__ inline void poll64(const unsigned* ring, int lane, unsigned tgt, int& budget) {
  const unsigned* a = ring + lane;
  for (;;) {
    unsigned v = __hip_atomic_load(a, __ATOMIC_RELAXED, __HIP_MEMORY_SCOPE_AGENT);
    if (__all((int)(v >= tgt))) break;
    if (--budget <= 0) break;
    __builtin_amdgcn_s_sleep(1);
  }
  asm volatile("" ::: "memory");
}

// ---------------- W_comb = W_ih[:,1:65] @ W_dec[:64,:]  (+ c0) ----------------
__global__ void wcomb_kernel(const float* __restrict__ W_ih, const float* __restrict__ W_dec,
                             const float* __restrict__ b_ih, const float* __restrict__ b_dec,
                             unsigned short* __restrict__ Wcomb, float* __restrict__ c0) {
  __shared__ float arow[64];
  int i = blockIdx.x;
  int tid = threadIdx.x;
  if (tid < 64) arow[tid] = W_ih[(size_t)i * 65 + 1 + tid];
  __syncthreads();
  for (int j = tid; j < H_; j += 256) {
    float acc = 0.f;
#pragma unroll 8
    for (int d = 0; d < 64; ++d) acc += arow[d] * W_dec[(size_t)d * H_ + j];
    Wcomb[(size_t)i * H_ + j] = f2bf(acc);
  }
  if (tid == 0) {
    float acc = b_ih[i];
    for (int d = 0; d < 64; ++d) acc += arow[d] * b_dec[d];
    c0[i] = acc;
  }
}

// ---------------- persistent recurrence: R8 protocol + fragment-layout slab ----------------
__global__ __launch_bounds__(128, 1) void rnn_persist(
    const float* __restrict__ xs, const float* __restrict__ ts,
    const float* __restrict__ W_ih, const float* __restrict__ W_hh,
    const float* __restrict__ b_ih, const float* __restrict__ b_hh,
    const float* __restrict__ W_dec, const float* __restrict__ b_dec,
    const int* __restrict__ cutoffp,
    const unsigned short* __restrict__ Wcomb, const float* __restrict__ c0,
    unsigned long long* __restrict__ hslabE, unsigned* __restrict__ cflags,
    float* __restrict__ out) {
  extern __shared__ char sm[];
  const int tid = threadIdx.x;
  const int wave = tid >> 6, lane = tid & 63;
  const int jl = lane & 15, kg = lane >> 4;
  const int cutoff = *cutoffp;

  const int bg = blockIdx.x & 7;
  const int cg = blockIdx.x >> 3;
  const int b0 = bg * 32;
  const int j0 = cg * JW;

  // ---- one-time LDS fill (weights, swizzled; R2-proven layout) ----
  for (int u = tid; u < NG * 64; u += 128) {
    int r = u >> 6, blk = u & 63;
    int grow = (r >> 4) * H_ + j0 + (r & 15);
    s16x8 v = cvt8(W_hh + (size_t)grow * H_ + blk * 8);
    *(s16x8*)(sm + OFF_WGH + r * 1024 + ((blk * 16) ^ ((r & 7) << 4))) = v;
  }
  for (int u = tid; u < NG * 64; u += 128) {
    int r = u >> 6, blk = u & 63;
    int grow = (r >> 4) * H_ + j0 + (r & 15);
    s16x8 v = *(const s16x8*)(Wcomb + (size_t)grow * H_ + blk * 8);
    *(s16x8*)(sm + OFF_WGI2 + r * 1024 + ((blk * 16) ^ ((r & 7) << 4))) = v;
  }
  for (int u = tid; u < NG * 8; u += 128) {
    int r = u >> 3, blk = u & 7;
    int grow = (r >> 4) * H_ + j0 + (r & 15);
    s16x8 v = cvt8(W_ih + (size_t)grow * 65 + 1 + blk * 8);
    *(s16x8*)(sm + OFF_WGIX + r * 128 + ((blk * 16) ^ ((r & 7) << 4))) = v;
  }
  if (cg < 8) {
    for (int u = tid; u < 16 * 64; u += 128) {
      int r = u >> 6, blk = u & 63;
      s16x8 v = cvt8(W_dec + (size_t)(cg * 16 + r) * H_ + blk * 8);
      *(s16x8*)(sm + OFF_WDEC + r * 1024 + ((blk * 16) ^ ((r & 7) << 4))) = v;
    }
    if (tid < 16) ((float*)(sm + OFF_BDECS))[tid] = b_dec[cg * 16 + tid];
  }
  if (tid < NG) {
    int grow = (tid >> 4) * H_ + j0 + (tid & 15);
    ((float*)(sm + OFF_W0S))[tid]  = W_ih[(size_t)grow * 65];
    ((float*)(sm + OFF_C0S))[tid]  = c0[grow];
    ((float*)(sm + OFF_BIHS))[tid] = b_ih[grow];
    ((float*)(sm + OFF_BHHS))[tid] = b_hh[grow];
  }
  __syncthreads();

  const int mt = wave;                          // M-tile: 16 rows per wave
  const int rowg = b0 + mt * 16 + jl;           // A-frag row (per lane)
  const int hrow = b0 + mt * 16 + kg * 4;       // C-tile row base (per lane)
  const unsigned* ring = cflags + bg * 64;
  unsigned* myflag = cflags + bg * 64 + cg * 2 + mt;
  unsigned short* scr = (unsigned short*)(sm + OFF_SCR) + mt * 256;
  int budget = 10000000;

  // fragment-layout slab bases (u64 units): [bg][mt][kc][kg][jl][w]
  const size_t bgmt = (size_t)bg * 4096 + (size_t)mt * 2048;
  // writer constants: kc = cg>>1, kg base = (cg&1)*2
  const size_t wbase = bgmt + (size_t)(cg >> 1) * 128 + (size_t)(cg & 1) * 64;
  const int kgi = lane >> 5, rem = lane & 31, wrow = rem >> 1, ww = rem & 1;

  const float* W0S  = (const float*)(sm + OFF_W0S);
  const float* C0S  = (const float*)(sm + OFF_C0S);
  const float* BIHS = (const float*)(sm + OFF_BIHS);
  const float* BHHS = (const float*)(sm + OFF_BHHS);
  const float w0r = W0S[jl],  w0z = W0S[16 + jl],  w0n = W0S[32 + jl];
  const float bir = BIHS[jl], biz = BIHS[16 + jl], bin_ = BIHS[32 + jl];
  const float c0r = C0S[jl],  c0z = C0S[16 + jl],  c0n = C0S[32 + jl];
  const float bhr = BHHS[jl], bhz = BHHS[16 + jl], bhn = BHHS[32 + jl];

  s16x8 whhf[3][16];
#pragma unroll
  for (int g = 0; g < 3; ++g)
#pragma unroll
    for (int kc = 0; kc < 16; ++kc)
      whhf[g][kc] = fragK512(sm + OFF_WGH, g * 16 + jl, kc, kg);

  const bool do_dec = (cg < 8);
  const float bd = do_dec ? ((const float*)(sm + OFF_BDECS))[jl] : 0.f;
  const int oc = cg * 16 + jl;                  // decode out-col

  float hp[4] = {0.f, 0.f, 0.f, 0.f};

  for (int t = 0; t < T_; ++t) {
    const bool use_x = (t < cutoff) || (t == 0);
    const unsigned long long* rq =
        hslabE + (size_t)((t + 1) & 1) * SLABW64 + bgmt;          // read h(t-1)
    unsigned long long* wq =
        hslabE + (size_t)(t & 1) * SLABW64 + wbase;               // write h(t)

    float tsv[4];
#pragma unroll
    for (int reg = 0; reg < 4; ++reg) tsv[reg] = ts[(size_t)(hrow + reg) * T_ + t];

    f32x4 g0{}, g1{}, g2{}, i0{}, i1{}, i2{};
    if (use_x) {                                 // xs-side gi: pre-poll
      s16x8 ax0 = cvt8(xs + ((size_t)rowg * T_ + t) * D_ + kg * 8);
      s16x8 ax1 = cvt8(xs + ((size_t)rowg * T_ + t) * D_ + 32 + kg * 8);
      i0 = mfma16(ax0, fragK64(sm + OFF_WGIX, jl,      0, kg), i0);
      i1 = mfma16(ax0, fragK64(sm + OFF_WGIX, 16 + jl, 0, kg), i1);
      i2 = mfma16(ax0, fragK64(sm + OFF_WGIX, 32 + jl, 0, kg), i2);
      i0 = mfma16(ax1, fragK64(sm + OFF_WGIX, jl,      1, kg), i0);
      i1 = mfma16(ax1, fragK64(sm + OFF_WGIX, 16 + jl, 1, kg), i1);
      i2 = mfma16(ax1, fragK64(sm + OFF_WGIX, 32 + jl, 1, kg), i2);
    }

    s16x8 a[16];
    if (t > 0) {
      poll64(ring, lane, (unsigned)t, budget);   // peers wrote h(t-1); slab t&1 free
      // coalesced fragment loads: wave reads contiguous 1KB per kc
#pragma unroll
      for (int kc = 0; kc < 16; ++kc)
        a[kc] = ld_frag2(rq + (size_t)kc * 128 + (size_t)kg * 32 + (size_t)jl * 2);
      if (!use_x) {
#pragma unroll
        for (int kc = 0; kc < 16; ++kc) {
          g0 = mfma16(a[kc], whhf[0][kc], g0);
          g1 = mfma16(a[kc], whhf[1][kc], g1);
          g2 = mfma16(a[kc], whhf[2][kc], g2);
          i0 = mfma16(a[kc], fragK512(sm + OFF_WGI2, jl,      kc, kg), i0);
          i1 = mfma16(a[kc], fragK512(sm + OFF_WGI2, 16 + jl, kc, kg), i1);
          i2 = mfma16(a[kc], fragK512(sm + OFF_WGI2, 32 + jl, kc, kg), i2);
        }
      } else {
#pragma unroll
        for (int kc = 0; kc < 16; ++kc) {
          g0 = mfma16(a[kc], whhf[0][kc], g0);
          g1 = mfma16(a[kc], whhf[1][kc], g1);
          g2 = mfma16(a[kc], whhf[2][kc], g2);
        }
      }
    }

    // GRU in-register (all 6 gate tiles share (lane,reg) layout)
    unsigned short hb[4];
#pragma unroll
    for (int reg = 0; reg < 4; ++reg) {
      const float xr = i0[reg] + tsv[reg] * w0r + (use_x ? bir : c0r) + g0[reg] + bhr;
      const float xz = i1[reg] + tsv[reg] * w0z + (use_x ? biz : c0z) + g1[reg] + bhz;
      const float an = i2[reg] + tsv[reg] * w0n + (use_x ? bin_ : c0n);
      const float gn = g2[reg] + bhn;
      const float r = 1.f / (1.f + __expf(-xr));
      const float z = 1.f / (1.f + __expf(-xz));
      const float e2 = __expf(2.f * (an + r * gn));
      const float n = 1.f - 2.f / (e2 + 1.f);
      const float hn = (1.f - z) * n + z * hp[reg];
      hp[reg] = hn;
      hb[reg] = f2bf(hn);
    }
    // in-wave 16x16 transpose via LDS scratch -> one coalesced 8B store/lane
#pragma unroll
    for (int reg = 0; reg < 4; ++reg) scr[(kg * 4 + reg) * 16 + jl] = hb[reg];
    asm volatile("s_waitcnt lgkmcnt(0)" ::: "memory");
    __builtin_amdgcn_sched_barrier(0);
    {
      unsigned long long pk =
          *(const unsigned long long*)(scr + wrow * 16 + kgi * 8 + ww * 4);
      st64a(wq + (size_t)kgi * 32 + (size_t)wrow * 2 + ww, pk);
    }
    asm volatile("s_waitcnt vmcnt(0)" ::: "memory");     // h at coherence point
    if (lane == 0)
      __hip_atomic_store(myflag, (unsigned)(t + 1),
                         __ATOMIC_RELAXED, __HIP_MEMORY_SCOPE_AGENT);

    // off-chain: decode step t-1 from register fragments (a[] = h(t-1))
    if (do_dec && t > 0) {
      f32x4 dacc{};
#pragma unroll
      for (int kc = 0; kc < 16; ++kc)
        dacc = mfma16(a[kc], fragK512(sm + OFF_WDEC, jl, kc, kg), dacc);
#pragma unroll
      for (int reg = 0; reg < 4; ++reg) {
        float vv = dacc[reg] + bd;
        if (oc >= D_) vv = fmaxf(vv, 0.001f);
        out[((size_t)(hrow + reg) * T_ + (t - 1)) * O_ + oc] = vv;
      }
    }
  }

  // epilogue: decode final step h(T-1)
  if (do_dec) {
    poll64(ring, lane, (unsigned)T_, budget);
    const unsigned long long* rq =
        hslabE + (size_t)((T_ - 1) & 1) * SLABW64 + bgmt;
    s16x8 a[16];
#pragma unroll
    for (int kc = 0; kc < 16; ++kc)
      a[kc] = ld_frag2(rq + (size_t)kc * 128 + (size_t)kg * 32 + (size_t)jl * 2);
    f32x4 dacc{};
#pragma unroll
    for (int kc = 0; kc < 16; ++kc)
      dacc = mfma16(a[kc], fragK512(sm + OFF_WDEC, jl, kc, kg), dacc);
#pragma unroll
    for (int reg = 0; reg < 4; ++reg) {
      float vv = dacc[reg] + bd;
      if (oc >= D_) vv = fmaxf(vv, 0.001f);
      out[((size_t)(hrow + reg) * T_ + (T_ - 1)) * O_ + oc] = vv;
    }
  }
}

extern "C" void kernel_launch(void* const* d_in, const int* in_sizes, int n_in,
                              void* d_out, int out_size, void* d_ws, size_t ws_size,
                              hipStream_t stream) {
  const float* xs    = (const float*)d_in[0];
  const float* ts    = (const float*)d_in[1];
  const float* W_ih  = (const float*)d_in[2];
  const float* W_hh  = (const float*)d_in[3];
  const float* b_ih  = (const float*)d_in[4];
  const float* b_hh  = (const float*)d_in[5];
  const float* W_dec = (const float*)d_in[6];
  const float* b_dec = (const float*)d_in[7];
  const int* cutoff  = (const int*)d_in[8];
  float* out = (float*)d_out;

  char* ws = (char*)d_ws;
  unsigned short* Wcomb      = (unsigned short*)(ws + WS_WCOMB);
  float* c0                  = (float*)(ws + WS_C0);
  unsigned long long* hslabE = (unsigned long long*)(ws + WS_HSLAB);
  unsigned* cflags           = (unsigned*)(ws + WS_CFLG);

  hipMemsetAsync(ws + WS_CFLG, 0, WS_CTLSZ, stream);
  wcomb_kernel<<<1536, 256, 0, stream>>>(W_ih, W_dec, b_ih, b_dec, Wcomb, c0);
  hipFuncSetAttribute(reinterpret_cast<const void*>(rnn_persist),
                      hipFuncAttributeMaxDynamicSharedMemorySize, SMEM_BYTES);
  rnn_persist<<<256, 128, SMEM_BYTES, stream>>>(xs, ts, W_ih, W_hh, b_ih, b_hh,
                                                W_dec, b_dec, cutoff, Wcomb, c0,
                                                hslabE, cflags, out);
}

// Round 13
// 4912.212 us; speedup vs baseline: 2.9297x; 1.0400x over previous
//
#include <hip/hip_runtime.h>
#include <hip/hip_bf16.h>
#include <cstdint>
#include <cstddef>

typedef float f32x4 __attribute__((ext_vector_type(4)));
typedef short s16x8 __attribute__((ext_vector_type(8)));

#define B_  256
#define T_  1024
#define D_  64
#define H_  512
#define O_  128
#define JW  16
#define NG  48

#define SLABW64 49152               // u64 words per slab: 16 blocks * 3072

// ---- LDS layout (bytes) ----
#define OFF_WGH   0                 // [48][512] bf16 W_hh rows (swizzled)
#define OFF_WGI2  49152             // [48][512] bf16 W_comb rows
#define OFF_WGIX  98304             // [48][64]  bf16 W_ih x-part
#define OFF_WDEC  104448            // [16][512] bf16 W_dec slice (cg<8)
#define OFF_W0S   120832
#define OFF_C0S   121024
#define OFF_BIHS  121216
#define OFF_BHHS  121408
#define OFF_BDECS 121600
#define OFF_SCR   121728            // 2 waves * 16x16 u16 scratch (1024B)
#define SMEM_BYTES 122752           // >80KB -> 1 WG/CU

// ---- workspace layout (bytes) ----
#define WS_WCOMB 0                  // [1536][512] bf16
#define WS_C0    1572864            // [1536] f32
#define WS_HSLAB 1579008            // 2 slabs * 393216 B (epoch-tagged h words)
#define WS_HSZ   786432

__device__ inline f32x4 mfma16(s16x8 a, s16x8 b, f32x4 c) {
  return __builtin_amdgcn_mfma_f32_16x16x32_bf16(a, b, c, 0, 0, 0);
}

__device__ inline unsigned short f2bf(float f) {
  __hip_bfloat16 h = __float2bfloat16(f);
  unsigned short u;
  __builtin_memcpy(&u, &h, sizeof(u));
  return u;
}

__device__ inline s16x8 cvt8(const float* s) {
  union { unsigned short h[8]; s16x8 v; } p;
#pragma unroll
  for (int e = 0; e < 8; ++e) p.h[e] = f2bf(s[e]);
  return p.v;
}

// B-fragment readers (rows K-contiguous, 16B-block XOR swizzle by (row&7)<<4)
__device__ inline s16x8 fragK512(const char* base, int n, int kc, int kg) {
  int byteoff = n * 1024 + (((kc * 64) + (kg * 16)) ^ ((n & 7) << 4));
  return *(const s16x8*)(base + byteoff);
}
__device__ inline s16x8 fragK64(const char* base, int n, int kc, int kg) {
  int byteoff = n * 128 + (((kc * 64) + (kg * 16)) ^ ((n & 7) << 4));
  return *(const s16x8*)(base + byteoff);
}

__device__ inline unsigned long long ld64a(const unsigned long long* p) {
  return __hip_atomic_load(p, __ATOMIC_RELAXED, __HIP_MEMORY_SCOPE_AGENT);
}
__device__ inline void st64a(unsigned long long* p, unsigned long long v) {
  __hip_atomic_store(p, v, __ATOMIC_RELAXED, __HIP_MEMORY_SCOPE_AGENT);
}

// 3 epoch-tagged words -> one 8-bf16 MFMA A-fragment (R9-proven)
__device__ inline s16x8 unpack3(unsigned long long w0, unsigned long long w1,
                                unsigned long long w2) {
  union { unsigned short u[8]; s16x8 v; } ua;
  ua.u[0] = (unsigned short)w0; ua.u[1] = (unsigned short)(w0 >> 16);
  ua.u[2] = (unsigned short)(w0 >> 32);
  ua.u[3] = (unsigned short)w1; ua.u[4] = (unsigned short)(w1 >> 16);
  ua.u[5] = (unsigned short)(w1 >> 32);
  ua.u[6] = (unsigned short)w2; ua.u[7] = (unsigned short)(w2 >> 16);
  return ua.v;
}

// group load: 4 kc * 3 words, coalesced (per kc the wave spans 1536B contiguous)
#define LOADG(W, KC0)                                                     \
  {                                                                       \
    _Pragma("unroll") for (int k_ = 0; k_ < 4; ++k_) {                    \
      W[k_ * 3 + 0] = ld64a(rqL + ((KC0) + k_) * 192 + 0);                \
      W[k_ * 3 + 1] = ld64a(rqL + ((KC0) + k_) * 192 + 1);                \
      W[k_ * 3 + 2] = ld64a(rqL + ((KC0) + k_) * 192 + 2);                \
    }                                                                     \
  }

// verify group epochs; on mismatch re-load the whole group (1 RT per retry)
#define VERIFY(W, KC0)                                                    \
  {                                                                       \
    for (;;) {                                                            \
      unsigned long long bad_ = 0;                                        \
      _Pragma("unroll") for (int i_ = 0; i_ < 12; ++i_)                   \
          bad_ |= (W[i_] >> 48) ^ tge;                                    \
      if (!__any((int)(bad_ != 0))) break;                                \
      if (--budget <= 0) break;                                           \
      LOADG(W, KC0)                                                       \
    }                                                                     \
  }

#define UNPACKG(W, KC0)                                                   \
  {                                                                       \
    _Pragma("unroll") for (int k_ = 0; k_ < 4; ++k_)                      \
        a[(KC0) + k_] =                                                   \
            unpack3(W[k_ * 3], W[k_ * 3 + 1], W[k_ * 3 + 2]);             \
  }

// ---------------- W_comb = W_ih[:,1:65] @ W_dec[:64,:]  (+ c0) ----------------
__global__ void wcomb_kernel(const float* __restrict__ W_ih, const float* __restrict__ W_dec,
                             const float* __restrict__ b_ih, const float* __restrict__ b_dec,
                             unsigned short* __restrict__ Wcomb, float* __restrict__ c0) {
  __shared__ float arow[64];
  int i = blockIdx.x;
  int tid = threadIdx.x;
  if (tid < 64) arow[tid] = W_ih[(size_t)i * 65 + 1 + tid];
  __syncthreads();
  for (int j = tid; j < H_; j += 256) {
    float acc = 0.f;
#pragma unroll 8
    for (int d = 0; d < 64; ++d) acc += arow[d] * W_dec[(size_t)d * H_ + j];
    Wcomb[(size_t)i * H_ + j] = f2bf(acc);
  }
  if (tid == 0) {
    float acc = b_ih[i];
    for (int d = 0; d < 64; ++d) acc += arow[d] * b_dec[d];
    c0[i] = acc;
  }
}

// ---------- persistent recurrence: coalesced epoch-in-data, pipelined groups ----------
__global__ __launch_bounds__(128, 1) void rnn_persist(
    const float* __restrict__ xs, const float* __restrict__ ts,
    const float* __restrict__ W_ih, const float* __restrict__ W_hh,
    const float* __restrict__ b_ih, const float* __restrict__ b_hh,
    const float* __restrict__ W_dec, const float* __restrict__ b_dec,
    const int* __restrict__ cutoffp,
    const unsigned short* __restrict__ Wcomb, const float* __restrict__ c0,
    unsigned long long* __restrict__ hslabE, float* __restrict__ out) {
  extern __shared__ char sm[];
  const int tid = threadIdx.x;
  const int wave = tid >> 6, lane = tid & 63;
  const int jl = lane & 15, kg = lane >> 4;
  const int cutoff = *cutoffp;

  const int bg = blockIdx.x & 7;
  const int cg = blockIdx.x >> 3;
  const int b0 = bg * 32;
  const int j0 = cg * JW;

  // ---- one-time LDS fill (weights, swizzled; R2-proven layout) ----
  for (int u = tid; u < NG * 64; u += 128) {
    int r = u >> 6, blk = u & 63;
    int grow = (r >> 4) * H_ + j0 + (r & 15);
    s16x8 v = cvt8(W_hh + (size_t)grow * H_ + blk * 8);
    *(s16x8*)(sm + OFF_WGH + r * 1024 + ((blk * 16) ^ ((r & 7) << 4))) = v;
  }
  for (int u = tid; u < NG * 64; u += 128) {
    int r = u >> 6, blk = u & 63;
    int grow = (r >> 4) * H_ + j0 + (r & 15);
    s16x8 v = *(const s16x8*)(Wcomb + (size_t)grow * H_ + blk * 8);
    *(s16x8*)(sm + OFF_WGI2 + r * 1024 + ((blk * 16) ^ ((r & 7) << 4))) = v;
  }
  for (int u = tid; u < NG * 8; u += 128) {
    int r = u >> 3, blk = u & 7;
    int grow = (r >> 4) * H_ + j0 + (r & 15);
    s16x8 v = cvt8(W_ih + (size_t)grow * 65 + 1 + blk * 8);
    *(s16x8*)(sm + OFF_WGIX + r * 128 + ((blk * 16) ^ ((r & 7) << 4))) = v;
  }
  if (cg < 8) {
    for (int u = tid; u < 16 * 64; u += 128) {
      int r = u >> 6, blk = u & 63;
      s16x8 v = cvt8(W_dec + (size_t)(cg * 16 + r) * H_ + blk * 8);
      *(s16x8*)(sm + OFF_WDEC + r * 1024 + ((blk * 16) ^ ((r & 7) << 4))) = v;
    }
    if (tid < 16) ((float*)(sm + OFF_BDECS))[tid] = b_dec[cg * 16 + tid];
  }
  if (tid < NG) {
    int grow = (tid >> 4) * H_ + j0 + (tid & 15);
    ((float*)(sm + OFF_W0S))[tid]  = W_ih[(size_t)grow * 65];
    ((float*)(sm + OFF_C0S))[tid]  = c0[grow];
    ((float*)(sm + OFF_BIHS))[tid] = b_ih[grow];
    ((float*)(sm + OFF_BHHS))[tid] = b_hh[grow];
  }
  __syncthreads();

  const int mt = wave;                          // M-tile: 16 rows per wave
  const int rowg = b0 + mt * 16 + jl;           // A-frag row (per lane)
  const int hrow = b0 + mt * 16 + kg * 4;       // C-tile row base (per lane)
  unsigned short* scr = (unsigned short*)(sm + OFF_SCR) + mt * 256;
  int budget = 200000;

  // slab bases (u64 units): block (bg,mt) = 3072 words, [kc][kg][jl][3]
  const size_t blkb = (size_t)(bg * 2 + mt) * 3072;
  const size_t laneoff = (size_t)kg * 48 + (size_t)jl * 3;
  // writer: kc = cg>>1, kg base = (cg&1)*2 (+fg)
  const int wi0 = lane;                          // slot = r*6 + fg*3 + pos
  const int wr0 = wi0 / 6, wk0 = wi0 % 6;
  const int wi1 = 64 + lane;
  const int wr1 = wi1 / 6, wk1 = wi1 % 6;

  const float* W0S  = (const float*)(sm + OFF_W0S);
  const float* C0S  = (const float*)(sm + OFF_C0S);
  const float* BIHS = (const float*)(sm + OFF_BIHS);
  const float* BHHS = (const float*)(sm + OFF_BHHS);
  const float w0r = W0S[jl],  w0z = W0S[16 + jl],  w0n = W0S[32 + jl];
  const float bir = BIHS[jl], biz = BIHS[16 + jl], bin_ = BIHS[32 + jl];
  const float c0r = C0S[jl],  c0z = C0S[16 + jl],  c0n = C0S[32 + jl];
  const float bhr = BHHS[jl], bhz = BHHS[16 + jl], bhn = BHHS[32 + jl];

  const bool do_dec = (cg < 8);
  const float bd = do_dec ? ((const float*)(sm + OFF_BDECS))[jl] : 0.f;
  const int oc = cg * 16 + jl;                  // decode out-col

  float hp[4] = {0.f, 0.f, 0.f, 0.f};

  for (int t = 0; t < T_; ++t) {
    const bool use_x = (t < cutoff) || (t == 0);
    const unsigned long long tge = (unsigned long long)(unsigned)t;  // epoch of h(t-1)
    const unsigned long long epw = (unsigned long long)(t + 1) << 48;
    const unsigned long long* rqL =
        hslabE + (size_t)((t + 1) & 1) * SLABW64 + blkb + laneoff;
    unsigned long long* wq = hslabE + (size_t)(t & 1) * SLABW64 + blkb;

    float tsv[4];
#pragma unroll
    for (int reg = 0; reg < 4; ++reg) tsv[reg] = ts[(size_t)(hrow + reg) * T_ + t];

    f32x4 g0{}, g1{}, g2{}, i0{}, i1{}, i2{};
    if (use_x) {                                 // xs-side gi: pre-exchange
      s16x8 ax0 = cvt8(xs + ((size_t)rowg * T_ + t) * D_ + kg * 8);
      s16x8 ax1 = cvt8(xs + ((size_t)rowg * T_ + t) * D_ + 32 + kg * 8);
      i0 = mfma16(ax0, fragK64(sm + OFF_WGIX, jl,      0, kg), i0);
      i1 = mfma16(ax0, fragK64(sm + OFF_WGIX, 16 + jl, 0, kg), i1);
      i2 = mfma16(ax0, fragK64(sm + OFF_WGIX, 32 + jl, 0, kg), i2);
      i0 = mfma16(ax1, fragK64(sm + OFF_WGIX, jl,      1, kg), i0);
      i1 = mfma16(ax1, fragK64(sm + OFF_WGIX, 16 + jl, 1, kg), i1);
      i2 = mfma16(ax1, fragK64(sm + OFF_WGIX, 32 + jl, 1, kg), i2);
    }

    s16x8 a[16];
    if (t > 0) {
      unsigned long long w0b[12], w1b[12];
      LOADG(w0b, 0)
      LOADG(w1b, 4)

#define MFMA_CL(K0)                                                          \
      { _Pragma("unroll") for (int k_ = 0; k_ < 4; ++k_) {                   \
          int kc_ = (K0) + k_;                                               \
          g0 = mfma16(a[kc_], fragK512(sm + OFF_WGH, jl,      kc_, kg), g0); \
          g1 = mfma16(a[kc_], fragK512(sm + OFF_WGH, 16 + jl, kc_, kg), g1); \
          g2 = mfma16(a[kc_], fragK512(sm + OFF_WGH, 32 + jl, kc_, kg), g2); \
          if (!use_x) {                                                      \
            i0 = mfma16(a[kc_], fragK512(sm + OFF_WGI2, jl,      kc_, kg), i0); \
            i1 = mfma16(a[kc_], fragK512(sm + OFF_WGI2, 16 + jl, kc_, kg), i1); \
            i2 = mfma16(a[kc_], fragK512(sm + OFF_WGI2, 32 + jl, kc_, kg), i2); \
          } } }

      VERIFY(w0b, 0)
      UNPACKG(w0b, 0)
      LOADG(w0b, 8)
      MFMA_CL(0)
      VERIFY(w1b, 4)
      UNPACKG(w1b, 4)
      LOADG(w1b, 12)
      MFMA_CL(4)
      VERIFY(w0b, 8)
      UNPACKG(w0b, 8)
      MFMA_CL(8)
      VERIFY(w1b, 12)
      UNPACKG(w1b, 12)
      MFMA_CL(12)
#undef MFMA_CL
    }

    // GRU in-register (all 6 gate tiles share (lane,reg) layout)
    unsigned short hb[4];
#pragma unroll
    for (int reg = 0; reg < 4; ++reg) {
      const float xr = i0[reg] + tsv[reg] * w0r + (use_x ? bir : c0r) + g0[reg] + bhr;
      const float xz = i1[reg] + tsv[reg] * w0z + (use_x ? biz : c0z) + g1[reg] + bhz;
      const float an = i2[reg] + tsv[reg] * w0n + (use_x ? bin_ : c0n);
      const float gn = g2[reg] + bhn;
      const float r = 1.f / (1.f + __expf(-xr));
      const float z = 1.f / (1.f + __expf(-xz));
      const float e2 = __expf(2.f * (an + r * gn));
      const float n = 1.f - 2.f / (e2 + 1.f);
      const float hn = (1.f - z) * n + z * hp[reg];
      hp[reg] = hn;
      hb[reg] = f2bf(hn);
    }

    // transpose via LDS scratch -> epoch-tagged coalesced stores (NO drain, NO flag)
#pragma unroll
    for (int reg = 0; reg < 4; ++reg) scr[(kg * 4 + reg) * 16 + jl] = hb[reg];
    asm volatile("s_waitcnt lgkmcnt(0)" ::: "memory");
    __builtin_amdgcn_sched_barrier(0);
    {
      // slot 0 (all lanes)
      const int fg = wk0 / 3, pos = wk0 % 3;
      const int cb = fg * 8 + pos * 3;
      unsigned long long v =
          (unsigned long long)scr[wr0 * 16 + cb] |
          ((unsigned long long)scr[wr0 * 16 + cb + 1] << 16) |
          (pos < 2 ? ((unsigned long long)scr[wr0 * 16 + cb + 2] << 32) : 0ull) |
          epw;
      st64a(wq + (size_t)(cg >> 1) * 192 +
                (size_t)((cg & 1) * 2 + fg) * 48 + (size_t)wr0 * 3 + pos, v);
    }
    if (lane < 32) {
      // slot 1 (lanes 0..31)
      const int fg = wk1 / 3, pos = wk1 % 3;
      const int cb = fg * 8 + pos * 3;
      unsigned long long v =
          (unsigned long long)scr[wr1 * 16 + cb] |
          ((unsigned long long)scr[wr1 * 16 + cb + 1] << 16) |
          (pos < 2 ? ((unsigned long long)scr[wr1 * 16 + cb + 2] << 32) : 0ull) |
          epw;
      st64a(wq + (size_t)(cg >> 1) * 192 +
                (size_t)((cg & 1) * 2 + fg) * 48 + (size_t)wr1 * 3 + pos, v);
    }

    // off-chain: decode step t-1 from register fragments (a[] = h(t-1))
    if (do_dec && t > 0) {
      f32x4 dacc{};
#pragma unroll
      for (int kc = 0; kc < 16; ++kc)
        dacc = mfma16(a[kc], fragK512(sm + OFF_WDEC, jl, kc, kg), dacc);
#pragma unroll
      for (int reg = 0; reg < 4; ++reg) {
        float vv = dacc[reg] + bd;
        if (oc >= D_) vv = fmaxf(vv, 0.001f);
        out[((size_t)(hrow + reg) * T_ + (t - 1)) * O_ + oc] = vv;
      }
    }
  }

  // epilogue: decode final step h(T-1)
  if (do_dec) {
    const unsigned long long tge = (unsigned long long)(unsigned)T_;
    const unsigned long long* rqL =
        hslabE + (size_t)((T_ - 1) & 1) * SLABW64 + blkb + laneoff;
    f32x4 dacc{};
    unsigned long long wv[12];
    s16x8 a[16];
#pragma unroll
    for (int grp = 0; grp < 4; ++grp) {
      LOADG(wv, grp * 4)
      VERIFY(wv, grp * 4)
      UNPACKG(wv, grp * 4)
#pragma unroll
      for (int k = 0; k < 4; ++k) {
        int kc = grp * 4 + k;
        dacc = mfma16(a[kc], fragK512(sm + OFF_WDEC, jl, kc, kg), dacc);
      }
    }
#pragma unroll
    for (int reg = 0; reg < 4; ++reg) {
      float vv = dacc[reg] + bd;
      if (oc >= D_) vv = fmaxf(vv, 0.001f);
      out[((size_t)(hrow + reg) * T_ + (T_ - 1)) * O_ + oc] = vv;
    }
  }
}

extern "C" void kernel_launch(void* const* d_in, const int* in_sizes, int n_in,
                              void* d_out, int out_size, void* d_ws, size_t ws_size,
                              hipStream_t stream) {
  const float* xs    = (const float*)d_in[0];
  const float* ts    = (const float*)d_in[1];
  const float* W_ih  = (const float*)d_in[2];
  const float* W_hh  = (const float*)d_in[3];
  const float* b_ih  = (const float*)d_in[4];
  const float* b_hh  = (const float*)d_in[5];
  const float* W_dec = (const float*)d_in[6];
  const float* b_dec = (const float*)d_in[7];
  const int* cutoff  = (const int*)d_in[8];
  float* out = (float*)d_out;

  char* ws = (char*)d_ws;
  unsigned short* Wcomb      = (unsigned short*)(ws + WS_WCOMB);
  float* c0                  = (float*)(ws + WS_C0);
  unsigned long long* hslabE = (unsigned long long*)(ws + WS_HSLAB);

  hipMemsetAsync(ws + WS_HSLAB, 0, WS_HSZ, stream);   // zero epochs (replay-safe)
  wcomb_kernel<<<1536, 256, 0, stream>>>(W_ih, W_dec, b_ih, b_dec, Wcomb, c0);
  hipFuncSetAttribute(reinterpret_cast<const void*>(rnn_persist),
                      hipFuncAttributeMaxDynamicSharedMemorySize, SMEM_BYTES);
  rnn_persist<<<256, 128, SMEM_BYTES, stream>>>(xs, ts, W_ih, W_hh, b_ih, b_hh,
                                                W_dec, b_dec, cutoff, Wcomb, c0,
                                                hslabE, out);
}